// Round 1
// baseline (185.934 us; speedup 1.0000x reference)
//
#include <hip/hip_runtime.h>
#include <math.h>

// Problem constants (from reference): B=4, T=512, IDIM=128, HDIM=1024, CDIM=256
#define NROWS   2048          // B*T
#define NITER   4             // HDIM/CDIM
#define IGNORE_OUT 10000.0f

// ---------- block reduction helpers (256 threads = 4 waves of 64) ----------

__device__ __forceinline__ float waveSum(float v){
  #pragma unroll
  for (int o = 32; o; o >>= 1) v += __shfl_down(v, o, 64);
  return v;
}

// result valid in ALL threads
__device__ __forceinline__ float blkSum(float v, float* red){
  v = waveSum(v);
  int lane = threadIdx.x & 63, wid = threadIdx.x >> 6;
  __syncthreads();                 // protect red reuse from previous reduction
  if (lane == 0) red[wid] = v;
  __syncthreads();
  return red[0] + red[1] + red[2] + red[3];
}

__device__ __forceinline__ float blkMax(float v, float* red){
  #pragma unroll
  for (int o = 32; o; o >>= 1) v = fmaxf(v, __shfl_down(v, o, 64));
  int lane = threadIdx.x & 63, wid = threadIdx.x >> 6;
  __syncthreads();
  if (lane == 0) red[wid] = v;
  __syncthreads();
  return fmaxf(fmaxf(red[0], red[1]), fmaxf(red[2], red[3]));
}

// first-occurrence argmax (numpy semantics): max value, ties -> smallest index
__device__ __forceinline__ int blkArgmaxFirst(float v, int idx, float* redv, int* redi){
  #pragma unroll
  for (int o = 32; o; o >>= 1){
    float ov = __shfl_down(v,   o, 64);
    int   oi = __shfl_down(idx, o, 64);
    if (ov > v || (ov == v && oi < idx)) { v = ov; idx = oi; }
  }
  int lane = threadIdx.x & 63, wid = threadIdx.x >> 6;
  __syncthreads();
  if (lane == 0){ redv[wid] = v; redi[wid] = idx; }
  __syncthreads();
  float bv = redv[0]; int bi = redi[0];
  #pragma unroll
  for (int w = 1; w < 4; ++w){
    float ov = redv[w]; int oi = redi[w];
    if (ov > bv || (ov == bv && oi < bi)) { bv = ov; bi = oi; }
  }
  return bi;
}

// ---------- kernel 1: M_i[d][o] = sum_{c in slice i} w1[c,d] * w2[o,c] ----------
// grid 512 = (i in 0..3) * 128 + o ; 128 threads = d
// w2 read is thread-uniform (scalar loads); w1 read coalesced over d.
// Mt layout: Mt[i*16384 + d*128 + o]  (so mainK reads coalesced over o)
__global__ void buildM(const float* __restrict__ w1, const float* __restrict__ w2,
                       float* __restrict__ Mt){
  int blk = blockIdx.x;
  int i = blk >> 7, o = blk & 127;
  int d = threadIdx.x;
  const float* w1p = w1 + (i * 256) * 128 + d;   // stride 128 over c
  const float* w2p = w2 + o * 1024 + i * 256;    // stride 1 over c, uniform
  float acc = 0.f;
  #pragma unroll 8
  for (int c = 0; c < 256; ++c)
    acc = fmaf(w1p[c * 128], w2p[c], acc);
  Mt[(i * 128 + d) * 128 + o] = acc;
}

// ---------- kernel 2: biasT[i][o] = b2[o] + sum_{c in slice i} b1[c]*w2[o,c] ----------
__global__ void biasK(const float* __restrict__ b1, const float* __restrict__ b2,
                      const float* __restrict__ w2, float* __restrict__ biasT){
  int i = blockIdx.x;
  int o = threadIdx.x;
  const float* w2p = w2 + o * 1024 + i * 256;
  const float* b1p = b1 + i * 256;
  float a = b2[o];
  #pragma unroll 8
  for (int c = 0; c < 256; ++c) a = fmaf(b1p[c], w2p[c], a);
  biasT[i * 128 + o] = a;
}

// ---------- kernel 3: per-row fused forward, 1 block per (b,t) row ----------
__global__ __launch_bounds__(256)
void mainK(const float* __restrict__ x, const float* __restrict__ y,
           const float* __restrict__ Mt, const float* __restrict__ biasT,
           float* __restrict__ acc){
  __shared__ float xr[128];     // x_res
  __shared__ float yr[128];     // y_res
  __shared__ float xatt[128];   // x_attn
  __shared__ float part[256];   // MLP partials
  __shared__ float redf[4];
  __shared__ int   redi[4];

  const int tid = threadIdx.x;
  const long base = (long)blockIdx.x * 128;

  float lossAcc = 0.f;
  float cnt = 0.f;
  bool  maskv = false;          // seq_mask for element o=tid (original y)
  if (tid < 128){
    xr[tid] = x[base + tid];
    float yv = y[base + tid];
    yr[tid] = yv;
    maskv = (yv == IGNORE_OUT);
    cnt = maskv ? 0.f : 1.f;
  }
  __syncthreads();

  for (int i = 0; i < NITER; ++i){
    // ---- ||y_res|| ----
    float sy = (tid < 128) ? yr[tid] * yr[tid] : 0.f;
    float ny2 = blkSum(sy, redf);
    float nY = sqrtf(ny2);

    // ---- sliding cross-correlation: thread s = tid (0..254) ----
    // kpt[s,d] = xr[s+d-127] for 0 <= s+d-127 < 128; loop only the valid d range
    float num = 0.f, nx2 = 0.f;
    {
      int s  = tid;
      int d0 = 127 - s; if (d0 < 0)   d0 = 0;
      int d1 = 254 - s; if (d1 > 127) d1 = 127;
      int jb = s - 127;
      for (int d = d0; d <= d1; ++d){
        float w = xr[jb + d];
        num = fmaf(yr[d], w, num);
        nx2 = fmaf(w, w, nx2);
      }
    }
    float den = nY * sqrtf(nx2);
    float sim = (den == 0.f) ? 0.f : num / den;
    if (tid >= 255) sim = -INFINITY;   // only 255 shifts exist
    int sstar = blkArgmaxFirst(sim, tid, redf, redi);

    // ---- x_aug + detached softmax attention ----
    float xa = 0.f, z = -INFINITY;
    if (tid < 128){
      int j = sstar + tid - 127;
      xa = ((unsigned)j < 128u) ? xr[j] : 0.f;
      z  = xa * yr[tid];
    }
    float mz = blkMax(z, redf);
    float e  = (tid < 128) ? expf(z - mz) : 0.f;
    float se = blkSum(e, redf);
    if (tid < 128) xatt[tid] = xa * (e / se);
    __syncthreads();   // xatt visible; also separates xr reads above from write below

    // ---- x_ele (reverse shift) and x_res update ----
    if (tid < 128){
      int j2 = tid + 127 - sstar;
      float xe = ((unsigned)j2 < 128u) ? xatt[j2] : 0.f;
      xr[tid] -= xe;   // next read of xr is next iteration (after loop-end barrier)
    }

    // ---- MLP via precomputed M_i: y_ele[o] = sum_d Mt[i][d][o] * xatt[d] ----
    {
      int o = tid & 127, half = tid >> 7;
      const float* Mi = Mt + i * 16384 + o;
      int dbeg = half * 64;
      float a2 = 0.f;
      #pragma unroll 8
      for (int d = 0; d < 64; ++d)
        a2 = fmaf(Mi[(dbeg + d) * 128], xatt[dbeg + d], a2);
      part[tid] = a2;
    }
    __syncthreads();
    if (tid < 128){
      float ye   = part[tid] + part[tid + 128] + biasT[i * 128 + tid];
      float diff = ye - yr[tid];
      if (!maskv) lossAcc = fmaf(diff, diff, lossAcc);
      yr[tid] = -diff;          // y_res - y_ele
    }
    __syncthreads();            // yr/xr writes drained before next iteration reads
  }

  float tot  = blkSum(lossAcc, redf);
  float totc = blkSum(cnt, redf);
  if (tid == 0){
    atomicAdd(&acc[0], tot);
    atomicAdd(&acc[1], totc);
  }
}

// ---------- kernel 4: finalize ----------
__global__ void finalize(const float* __restrict__ acc, float* __restrict__ out){
  if (threadIdx.x == 0 && blockIdx.x == 0)
    out[0] = acc[0] / ((float)NITER * acc[1]);
}

extern "C" void kernel_launch(void* const* d_in, const int* in_sizes, int n_in,
                              void* d_out, int out_size, void* d_ws, size_t ws_size,
                              hipStream_t stream){
  const float* x  = (const float*)d_in[0];
  const float* y  = (const float*)d_in[1];
  const float* w1 = (const float*)d_in[2];
  const float* b1 = (const float*)d_in[3];
  const float* w2 = (const float*)d_in[4];
  const float* b2 = (const float*)d_in[5];
  float* out = (float*)d_out;

  // workspace layout: [0,8): loss/count accumulators ; [256, 256+256K): Mt ; then biasT
  float* accp  = (float*)d_ws;
  float* Mt    = (float*)((char*)d_ws + 256);
  float* biasT = (float*)((char*)d_ws + 256 + 4 * 128 * 128 * sizeof(float));

  hipMemsetAsync(d_ws, 0, 2 * sizeof(float), stream);
  buildM<<<512, 128, 0, stream>>>(w1, w2, Mt);
  biasK<<<4, 128, 0, stream>>>(b1, b2, w2, biasT);
  mainK<<<NROWS, 256, 0, stream>>>(x, y, Mt, biasT, accp);
  finalize<<<1, 64, 0, stream>>>(accp, out);
}